// Round 2
// baseline (1181.877 us; speedup 1.0000x reference)
//
#include <hip/hip_runtime.h>

// FUSE hydrological model: T=8192 sequential steps, H=4096 independent chains.
// One thread per chain; rotating register prefetch (depth U) hides HBM latency.
// No <math.h>: glibc's __MATHCALL macros collide with __exp2f/__log2f names.

constexpr int T = 8192;
constexpr int H = 4096;
constexpr float EPS = 1e-6f;
constexpr int U = 16;   // unroll factor == prefetch depth

__device__ __forceinline__ float hw_log2(float x)  { return __builtin_amdgcn_logf(x); }   // v_log_f32
__device__ __forceinline__ float hw_exp2(float x)  { return __builtin_amdgcn_exp2f(x); }  // v_exp_f32
__device__ __forceinline__ float clampf(float x, float lo, float hi) {
    return __builtin_fminf(__builtin_fmaxf(x, lo), hi);
}

__global__ __launch_bounds__(64, 1)
void fuse_scan_kernel(const float* __restrict__ forcing,
                      const float* __restrict__ initial_state,
                      const float* __restrict__ raw_params,
                      const float* __restrict__ lo,
                      const float* __restrict__ hi,
                      float* __restrict__ out)
{
    const int h = blockIdx.x * blockDim.x + threadIdx.x;
    if (h >= H) return;

    // --- parameter unconstraining: phys = lo + (hi-lo)*sigmoid(raw) ---
    constexpr float LOG2E = 1.4426950408889634f;
    float ph[6];
#pragma unroll
    for (int j = 0; j < 6; ++j) {
        float r = raw_params[h * 6 + j];
        float s = 1.0f / (1.0f + hw_exp2(-r * LOG2E));   // sigmoid via 2^x
        ph[j] = lo[j] + (hi[j] - lo[j]) * s;
    }
    const float m1      = ph[0];
    const float m2      = ph[1];
    const float percrte = ph[2];
    const float baserte = ph[3];
    const float qpow    = ph[4];
    const float bexp    = ph[5];
    const float inv_m1  = 1.0f / m1;
    const float inv_m2  = 1.0f / m2;

    float s1 = initial_state[h * 2 + 0];
    float s2 = initial_state[h * 2 + 1];

    const float* __restrict__ f = forcing + (size_t)h * 3;
    const size_t fstride = (size_t)H * 3;   // floats per timestep

    // rotating prefetch buffers (fully unrolled static indices -> registers)
    float pb[U], eb[U];
#pragma unroll
    for (int k = 0; k < U; ++k) {
        pb[k] = f[(size_t)k * fstride + 0];
        eb[k] = f[(size_t)k * fstride + 1];
    }

    float* __restrict__ o = out + h;

    for (int t = 0; t < T; t += U) {
#pragma unroll
        for (int k = 0; k < U; ++k) {
            const float p   = pb[k];
            const float pet = eb[k];

            // prefetch timestep t+k+U (tail re-reads T-1 harmlessly)
            int tn = t + k + U;
            if (tn >= T) tn = T - 1;
            pb[k] = f[(size_t)tn * fstride + 0];
            eb[k] = f[(size_t)tn * fstride + 1];

            // --- one FUSE step ---
            float r1 = clampf(s1 * inv_m1, EPS, 1.0f);
            float r2 = clampf(s2 * inv_m2, EPS, 1.0f);
            float pw1 = hw_exp2(bexp * hw_log2(r1));   // r1^axv_bexp
            float pw2 = hw_exp2(qpow * hw_log2(r2));   // r2^qb_powr
            float qsx = pw1 * p;
            float e1  = pet * r1;
            float q12 = percrte * r1;
            float qb  = baserte * pw2;
            s1 = clampf(s1 + (p - qsx - e1 - q12), 0.0f, m1);
            s2 = clampf(s2 + (q12 - qb), 0.0f, m2);

            o[(size_t)(t + k) * H] = qsx + qb;   // DT = 1
        }
    }
}

extern "C" void kernel_launch(void* const* d_in, const int* in_sizes, int n_in,
                              void* d_out, int out_size, void* d_ws, size_t ws_size,
                              hipStream_t stream) {
    const float* forcing       = (const float*)d_in[0];  // (T, H, 3)
    const float* initial_state = (const float*)d_in[1];  // (H, 2)
    const float* raw_params    = (const float*)d_in[2];  // (H, 6)
    const float* param_lower   = (const float*)d_in[3];  // (6,)
    const float* param_upper   = (const float*)d_in[4];  // (6,)
    float* out = (float*)d_out;                          // (T, H)

    fuse_scan_kernel<<<dim3(H / 64), dim3(64), 0, stream>>>(
        forcing, initial_state, raw_params, param_lower, param_upper, out);
}